// Round 8
// baseline (776.447 us; speedup 1.0000x reference)
//
#include <hip/hip_runtime.h>

// ============================================================================
// KnowledgeGraphEncoder: 2-layer dense GAT, N=4096, H=4.
// bf16 MFMA merged projection GEMMs (BK=64, XOR-swizzled LDS);
// fp8(e4m3, per-row-max P) MFMA attention GEMMs, BK=64, split-K=2,
// raw atomicAdd epilogue (scale/elu folded into LN kernels);
// fused 8-way s-kernels; XCD-aware grids. ws ~213 MB.
// ============================================================================

typedef unsigned short u16;
typedef unsigned char u8;
using short8  = __attribute__((ext_vector_type(8))) short;
using float4v = __attribute__((ext_vector_type(4))) float;
using long2v  = __attribute__((ext_vector_type(2))) long;

#define NN 4096
#define NHEADS 4

__device__ __forceinline__ u16 f2bf(float f) {
  union { float f; unsigned u; } v; v.f = f;
  unsigned u = v.u;
  return (u16)((u + 0x7FFFu + ((u >> 16) & 1u)) >> 16);   // RNE
}
__device__ __forceinline__ float bf2f(u16 x) {
  union { unsigned u; float f; } v; v.u = ((unsigned)x) << 16; return v.f;
}
// pack 4 floats -> 4 fp8 e4m3 bytes (HW cvt, OCP on gfx950)
__device__ __forceinline__ unsigned pk_fp8x4(float a, float b, float c, float d) {
  int lo = __builtin_amdgcn_cvt_pk_fp8_f32(a, b, 0, false);
  return (unsigned)__builtin_amdgcn_cvt_pk_fp8_f32(c, d, lo, true);
}

// async global->LDS, 16B per lane, LDS dest = wave-uniform base + lane*16
__device__ __forceinline__ void async16(const void* g, void* l) {
  __builtin_amdgcn_global_load_lds(
      (const __attribute__((address_space(1))) unsigned int*)g,
      (__attribute__((address_space(3))) unsigned int*)l, 16, 0, 0);
}

// ---------------------------------------------------------------- cast fp32->bf16
__global__ __launch_bounds__(256) void cast_f32_bf16(const float* __restrict__ in,
                                                     u16* __restrict__ out, int n) {
  int i = blockIdx.x * 256 + threadIdx.x;
  if (i < n) out[i] = f2bf(in[i]);
}

// ------------------------------------------------- transpose+cast fp32 -> bf16
// in [z][R][C] -> out [z][C][R]
__global__ __launch_bounds__(256) void transcast_f32(const float* __restrict__ in,
                                                     u16* __restrict__ out, int R, int C) {
  __shared__ float t[32][33];
  size_t zoff = (size_t)blockIdx.z * R * C;
  in += zoff; out += zoff;
  int c0 = blockIdx.x * 32, r0 = blockIdx.y * 32;
  int tx = threadIdx.x & 31, ty = threadIdx.x >> 5;
#pragma unroll
  for (int i = 0; i < 32; i += 8)
    t[ty + i][tx] = in[(size_t)(r0 + ty + i) * C + (c0 + tx)];
  __syncthreads();
#pragma unroll
  for (int i = 0; i < 32; i += 8)
    out[(size_t)(c0 + ty + i) * R + (r0 + tx)] = f2bf(t[tx][ty + i]);
}

// ------------------------------------------------- wa[side][h][f] = sum_o W[h][f][o]*a[h][side*O+o]
__global__ __launch_bounds__(256) void wa_kernel(const float* __restrict__ W,
                                                 const float* __restrict__ a,
                                                 float* __restrict__ wa, int F, int O) {
  int gw = blockIdx.x * 4 + (threadIdx.x >> 6);
  int lane = threadIdx.x & 63;
  int total = 2 * NHEADS * F;
  if (gw >= total) return;
  int side = gw / (NHEADS * F);
  int rem = gw - side * NHEADS * F;
  int h = rem / F, f = rem - h * F;
  const float* wrow = W + ((size_t)h * F + f) * O;
  const float* av = a + (size_t)h * 2 * O + (size_t)side * O;
  float s = 0.f;
  for (int o = lane; o < O; o += 64) s += wrow[o] * av[o];
#pragma unroll
  for (int off = 32; off > 0; off >>= 1) s += __shfl_down(s, off);
  if (lane == 0) wa[gw] = s;
}

// ------------------------------------------------- fused 8-way s: one wave per node
__global__ __launch_bounds__(256) void s8_kernel_f32(const float* __restrict__ X,
                                                     const float* __restrict__ wa,
                                                     float* __restrict__ sout, int F) {
  int n = blockIdx.x * 4 + (threadIdx.x >> 6);
  int lane = threadIdx.x & 63;
  const float* x = X + (size_t)n * F;
  float acc[8] = {};
  for (int f = lane; f < F; f += 64) {
    float xv = x[f];
#pragma unroll
    for (int k = 0; k < 8; k++) acc[k] += xv * wa[(size_t)k * F + f];
  }
#pragma unroll
  for (int k = 0; k < 8; k++) {
    float s = acc[k];
#pragma unroll
    for (int off = 32; off > 0; off >>= 1) s += __shfl_down(s, off);
    if (lane == 0) sout[(size_t)k * NN + n] = s;
  }
}

__global__ __launch_bounds__(256) void s8_kernel_bf16(const u16* __restrict__ X,
                                                      const float* __restrict__ wa,
                                                      float* __restrict__ sout, int F) {
  int n = blockIdx.x * 4 + (threadIdx.x >> 6);
  int lane = threadIdx.x & 63;
  const u16* x = X + (size_t)n * F;
  float acc[8] = {};
  for (int f = lane; f < F; f += 64) {
    float xv = bf2f(x[f]);
#pragma unroll
    for (int k = 0; k < 8; k++) acc[k] += xv * wa[(size_t)k * F + f];
  }
#pragma unroll
  for (int k = 0; k < 8; k++) {
    float s = acc[k];
#pragma unroll
    for (int off = 32; off > 0; off >>= 1) s += __shfl_down(s, off);
    if (lane == 0) sout[(size_t)k * NN + n] = s;
  }
}

// ------------------------------------------------- G-head P' = exp(v - rowmax) fp8, l = rowsum (fp32)
template <int G>
__global__ __launch_bounds__(256) void pexp_g_kernel(const int* __restrict__ adj,
                                                     const float* __restrict__ ew,
                                                     const float* __restrict__ s,
                                                     u8* __restrict__ P,
                                                     float* __restrict__ L, int hb) {
  __shared__ float vbuf[G][NN];
  __shared__ float mred[G][4];
  __shared__ float lred[G][4];
  __shared__ float mrow[G];
  int i = blockIdx.x, tid = threadIdx.x;
  float sr[G], mx[G], lacc[G];
#pragma unroll
  for (int z = 0; z < G; z++) {
    sr[z] = s[(size_t)(hb + z) * NN + i];
    mx[z] = -3e38f;
    lacc[z] = 0.f;
  }
  const int4* arow = (const int4*)(adj + (size_t)i * NN);
  const float4* wrow = (const float4*)(ew + (size_t)i * NN);
  // pass 1: v -> LDS, row max
  for (int jv = tid; jv < NN / 4; jv += 256) {
    int4 a = arow[jv];
    float4 w = wrow[jv];
    int j0 = jv * 4;
    float we[4]; we[0] = w.x; we[1] = w.y; we[2] = w.z; we[3] = w.w;
    bool m[4];
    m[0] = (a.x != 0) || (j0 + 0 == i);
    m[1] = (a.y != 0) || (j0 + 1 == i);
    m[2] = (a.z != 0) || (j0 + 2 == i);
    m[3] = (a.w != 0) || (j0 + 3 == i);
#pragma unroll
    for (int z = 0; z < G; z++) {
      const float4 sd4 = *(const float4*)(s + (size_t)(NHEADS + hb + z) * NN + j0);
      float sd[4]; sd[0] = sd4.x; sd[1] = sd4.y; sd[2] = sd4.z; sd[3] = sd4.w;
      float4 vv;
      float* vp = (float*)&vv;
#pragma unroll
      for (int k = 0; k < 4; k++) {
        float x = sr[z] + sd[k];
        float e = x > 0.f ? x : 0.2f * x;
        float v = (m[k] ? e : -9e15f) * we[k];
        vp[k] = v;
        mx[z] = fmaxf(mx[z], v);
      }
      *(float4*)(&vbuf[z][j0]) = vv;
    }
  }
#pragma unroll
  for (int z = 0; z < G; z++) {
    float r = mx[z];
#pragma unroll
    for (int off = 32; off > 0; off >>= 1) r = fmaxf(r, __shfl_down(r, off));
    if ((tid & 63) == 0) mred[z][tid >> 6] = r;
  }
  __syncthreads();
  if (tid < G)
    mrow[tid] = fmaxf(fmaxf(mred[tid][0], mred[tid][1]), fmaxf(mred[tid][2], mred[tid][3]));
  __syncthreads();
  float mv[G];
#pragma unroll
  for (int z = 0; z < G; z++) mv[z] = mrow[z];
  // pass 2: p = exp(v - m), fp8 pack, rowsum
  for (int jv = tid; jv < NN / 4; jv += 256) {
    int j0 = jv * 4;
#pragma unroll
    for (int z = 0; z < G; z++) {
      float4 vv = *(const float4*)(&vbuf[z][j0]);
      float p0 = __expf(vv.x - mv[z]);
      float p1 = __expf(vv.y - mv[z]);
      float p2 = __expf(vv.z - mv[z]);
      float p3 = __expf(vv.w - mv[z]);
      lacc[z] += (p0 + p1) + (p2 + p3);
      *(unsigned*)(P + ((size_t)z * NN + i) * NN + j0) = pk_fp8x4(p0, p1, p2, p3);
    }
  }
#pragma unroll
  for (int z = 0; z < G; z++) {
    float r = lacc[z];
#pragma unroll
    for (int off = 32; off > 0; off >>= 1) r += __shfl_down(r, off);
    if ((tid & 63) == 0) lred[z][tid >> 6] = r;
  }
  __syncthreads();
  if (tid < G)
    L[(size_t)(hb + tid) * NN + i] = lred[tid][0] + lred[tid][1] + lred[tid][2] + lred[tid][3];
}

// ------------------------------------------------- merged projection GEMM (bf16, BK=64, XOR swizzle)
__global__ __launch_bounds__(256) void gemm_proj(const u16* __restrict__ A,
                                                 const u16* __restrict__ Bt,
                                                 u8* __restrict__ F8T,
                                                 float* __restrict__ F32,
                                                 const float* __restrict__ bias,
                                                 int K, int split, int ldcF) {
  int row0 = blockIdx.x * 128;
  int col0 = blockIdx.y * 128;

  __shared__ u16 ldsA[128 * 64];
  __shared__ u16 ldsB[128 * 64];

  int tid = threadIdx.x;
  int wave = tid >> 6, lane = tid & 63;
  int wm = wave >> 1, wn = wave & 1;
  int lm = lane & 15, quad = lane >> 4;

  int sr = tid >> 3, sc = tid & 7;
  int scg = sc ^ (sr & 7);                       // fetch swizzled global chunk
  const u16* aPtr = A  + (size_t)(row0 + sr) * K + scg * 8;
  const u16* bPtr = Bt + (size_t)(col0 + sr) * K + scg * 8;
  u16* ldsAw = &ldsA[wave * 512];
  u16* ldsBw = &ldsB[wave * 512];
  const size_t rowStep = (size_t)32 * K;

  float4v acc[4][4] = {};

  for (int k0 = 0; k0 < K; k0 += 64) {
    __syncthreads();
#pragma unroll
    for (int b = 0; b < 4; b++) {
      async16(aPtr + k0 + b * rowStep, ldsAw + b * 2048);
      async16(bPtr + k0 + b * rowStep, ldsBw + b * 2048);
    }
    __syncthreads();
    short8 af[4][2], bf[4][2];
#pragma unroll
    for (int s = 0; s < 4; s++) {
      int ra = wm * 64 + s * 16 + lm;
      int rb = wn * 64 + s * 16 + lm;
      int swa = ra & 7, swb = rb & 7;
      af[s][0] = *(const short8*)(&ldsA[ra * 64 + ((quad ^ swa) * 8)]);
      af[s][1] = *(const short8*)(&ldsA[ra * 64 + (((4 + quad) ^ swa) * 8)]);
      bf[s][0] = *(const short8*)(&ldsB[rb * 64 + ((quad ^ swb) * 8)]);
      bf[s][1] = *(const short8*)(&ldsB[rb * 64 + (((4 + quad) ^ swb) * 8)]);
    }
#pragma unroll
    for (int i = 0; i < 4; i++)
#pragma unroll
      for (int j = 0; j < 4; j++) {
        acc[i][j] = __builtin_amdgcn_mfma_f32_16x16x32_bf16(af[i][0], bf[j][0], acc[i][j], 0, 0, 0);
        acc[i][j] = __builtin_amdgcn_mfma_f32_16x16x32_bf16(af[i][1], bf[j][1], acc[i][j], 0, 0, 0);
      }
  }

  if (col0 < split) {
#pragma unroll
    for (int i = 0; i < 4; i++) {
#pragma unroll
      for (int j = 0; j < 4; j++) {
        int grow0 = row0 + wm * 64 + i * 16 + (lane >> 4) * 4;
        int gcol = col0 + wn * 64 + j * 16 + lm;
        unsigned pk = pk_fp8x4(acc[i][j][0], acc[i][j][1], acc[i][j][2], acc[i][j][3]);
        *(unsigned*)&F8T[(size_t)gcol * NN + grow0] = pk;
      }
    }
  } else {
#pragma unroll
    for (int i = 0; i < 4; i++) {
#pragma unroll
      for (int j = 0; j < 4; j++) {
#pragma unroll
        for (int r = 0; r < 4; r++) {
          int grow = row0 + wm * 64 + i * 16 + (lane >> 4) * 4 + r;
          int gcol = col0 + wn * 64 + j * 16 + lm - split;
          F32[(size_t)grow * ldcF + gcol] = acc[i][j][r] + bias[gcol];
        }
      }
    }
  }
}

// ------------------------------------------------- 128x128 fp8 MFMA GEMM, BK=64, split-K=2
// blockIdx.z = hrel*2 + kslice. Raw accumulation: atomicAdd of acc (no scaling).
// MODE 2: atomicAdd(C[grow*ldc + coloff_base + hrel*coloff_step + gcol], v)
// MODE 3: atomicAdd(C[hrel*cStride + grow*ldc + gcol], v)
template <int MODE>
__global__ __launch_bounds__(256) void gemm_fp8(const u8* __restrict__ A,
                                                const u8* __restrict__ Bt,
                                                float* __restrict__ Cout,
                                                int ldc, int coloff_base, int coloff_step,
                                                size_t bStride, size_t cStride) {
  constexpr int K = NN;
  int hrel = blockIdx.z >> 1;
  int ks = blockIdx.z & 1;
  const u8* Ab = A + (size_t)hrel * ((size_t)NN * NN);
  const u8* Bb = Bt + (size_t)hrel * bStride;
  int row0 = blockIdx.x * 128;
  int col0 = blockIdx.y * 128;
  int coloff = coloff_base + hrel * coloff_step;

  __shared__ u8 ldsA[128 * 64];
  __shared__ u8 ldsB[128 * 64];

  int tid = threadIdx.x;
  int wave = tid >> 6, lane = tid & 63;
  int wm = wave >> 1, wn = wave & 1;
  int lm = lane & 15, q16 = (lane >> 4) * 16;

  const u8* aPtr = Ab + (size_t)(row0 + (tid >> 2)) * K + ((tid & 3) * 16);
  const u8* bPtr = Bb + (size_t)(col0 + (tid >> 2)) * K + ((tid & 3) * 16);
  u8* ldsAw = &ldsA[wave * 1024];
  u8* ldsBw = &ldsB[wave * 1024];
  const size_t rowStep = (size_t)64 * K;

  float4v acc[4][4] = {};

  const int kbeg = ks * (K / 2), kend = kbeg + K / 2;
  for (int k0 = kbeg; k0 < kend; k0 += 64) {
    __syncthreads();
    async16(aPtr + k0,           ldsAw);           // rows 0-63
    async16(aPtr + k0 + rowStep, ldsAw + 4096);    // rows 64-127
    async16(bPtr + k0,           ldsBw);
    async16(bPtr + k0 + rowStep, ldsBw + 4096);
    __syncthreads();
    long2v a16[4], b16[4];
#pragma unroll
    for (int s = 0; s < 4; s++) {
      a16[s] = *(const long2v*)(&ldsA[(wm * 64 + s * 16 + lm) * 64 + q16]);
      b16[s] = *(const long2v*)(&ldsB[(wn * 64 + s * 16 + lm) * 64 + q16]);
    }
#pragma unroll
    for (int i = 0; i < 4; i++)
#pragma unroll
      for (int j = 0; j < 4; j++) {
        acc[i][j] = __builtin_amdgcn_mfma_f32_16x16x32_fp8_fp8(a16[i][0], b16[j][0], acc[i][j], 0, 0, 0);
        acc[i][j] = __builtin_amdgcn_mfma_f32_16x16x32_fp8_fp8(a16[i][1], b16[j][1], acc[i][j], 0, 0, 0);
      }
  }

#pragma unroll
  for (int i = 0; i < 4; i++) {
#pragma unroll
    for (int j = 0; j < 4; j++) {
#pragma unroll
      for (int r = 0; r < 4; r++) {
        int grow = row0 + wm * 64 + i * 16 + (lane >> 4) * 4 + r;
        int gcol = col0 + wn * 64 + j * 16 + lm;
        float v = acc[i][j][r];
        if constexpr (MODE == 2) {
          atomicAdd(&Cout[(size_t)grow * ldc + coloff + gcol], v);
        } else {
          atomicAdd(&Cout[(size_t)hrel * cStride + (size_t)grow * ldc + gcol], v);
        }
      }
    }
  }
}

// ------------------------------------------------- LN layer 0: x = RP0 + elu(ACC0/l) -> LN -> elu -> bf16
__global__ __launch_bounds__(256) void ln0_kernel(const float* __restrict__ accin,
                                                  const float* __restrict__ rp,
                                                  const float* __restrict__ Lsum,
                                                  const float* __restrict__ g,
                                                  const float* __restrict__ b,
                                                  u16* __restrict__ h1b) {
  const int C = 2048;
  int n = blockIdx.x, tid = threadIdx.x;
  __shared__ float xs[2048];
  __shared__ float red[2][4];
  __shared__ float mrs[2];
  float linv[NHEADS];
#pragma unroll
  for (int h = 0; h < NHEADS; h++) linv[h] = 1.0f / Lsum[(size_t)h * NN + n];
  float sum = 0.f, sq = 0.f;
  const float* ar = accin + (size_t)n * C;
  const float* rr = rp + (size_t)n * C;
  for (int c = tid; c < C; c += 256) {
    float v = ar[c] * linv[c >> 9];
    v = v > 0.f ? v : (__expf(v) - 1.f);
    float x = v + rr[c];
    xs[c] = x; sum += x; sq += x * x;
  }
#pragma unroll
  for (int off = 32; off > 0; off >>= 1) { sum += __shfl_down(sum, off); sq += __shfl_down(sq, off); }
  if ((tid & 63) == 0) { red[0][tid >> 6] = sum; red[1][tid >> 6] = sq; }
  __syncthreads();
  if (tid == 0) {
    float s = red[0][0] + red[0][1] + red[0][2] + red[0][3];
    float q = red[1][0] + red[1][1] + red[1][2] + red[1][3];
    float mean = s / C, var = q / C - mean * mean;
    mrs[0] = mean; mrs[1] = rsqrtf(var + 1e-5f);
  }
  __syncthreads();
  float mean = mrs[0], rstd = mrs[1];
  for (int c = tid; c < C; c += 256) {
    float y = (xs[c] - mean) * rstd * g[c] + b[c];
    float z = y > 0.f ? y : (__expf(y) - 1.f);
    h1b[(size_t)n * C + c] = f2bf(z);
  }
}

// ------------------------------------------------- LN layer 1: x = 0.25*sum_h HP1[h]/l1[h] + rp1 -> LN
__global__ __launch_bounds__(256) void ln1_kernel(const float* __restrict__ hp1,
                                                  const float* __restrict__ rp1,
                                                  const float* __restrict__ Lsum,
                                                  const float* __restrict__ g,
                                                  const float* __restrict__ b,
                                                  float* __restrict__ out) {
  const int C = 768;
  int n = blockIdx.x, tid = threadIdx.x;
  __shared__ float xs[768];
  __shared__ float red[2][4];
  __shared__ float mrs[2];
  float linv[NHEADS];
#pragma unroll
  for (int h = 0; h < NHEADS; h++) linv[h] = 0.25f / Lsum[(size_t)h * NN + n];
  float sum = 0.f, sq = 0.f;
  for (int c = tid; c < C; c += 256) {
    float x = hp1[((size_t)0 * NN + n) * C + c] * linv[0] +
              hp1[((size_t)1 * NN + n) * C + c] * linv[1] +
              hp1[((size_t)2 * NN + n) * C + c] * linv[2] +
              hp1[((size_t)3 * NN + n) * C + c] * linv[3];
    x += rp1[(size_t)n * C + c];     // bias already folded into rp1 by gemm_proj
    xs[c] = x; sum += x; sq += x * x;
  }
#pragma unroll
  for (int off = 32; off > 0; off >>= 1) { sum += __shfl_down(sum, off); sq += __shfl_down(sq, off); }
  if ((tid & 63) == 0) { red[0][tid >> 6] = sum; red[1][tid >> 6] = sq; }
  __syncthreads();
  if (tid == 0) {
    float s = red[0][0] + red[0][1] + red[0][2] + red[0][3];
    float q = red[1][0] + red[1][1] + red[1][2] + red[1][3];
    float mean = s / C, var = q / C - mean * mean;
    mrs[0] = mean; mrs[1] = rsqrtf(var + 1e-5f);
  }
  __syncthreads();
  float mean = mrs[0], rstd = mrs[1];
  for (int c = tid; c < C; c += 256)
    out[(size_t)n * C + c] = (xs[c] - mean) * rstd * g[c] + b[c];
}

// ============================================================================
extern "C" void kernel_launch(void* const* d_in, const int* in_sizes, int n_in,
                              void* d_out, int out_size, void* d_ws, size_t ws_size,
                              hipStream_t stream) {
  (void)in_sizes; (void)n_in; (void)out_size;
  const float* X    = (const float*)d_in[0];
  const int*   adj  = (const int*)d_in[1];
  const float* ew   = (const float*)d_in[2];
  const float* W0   = (const float*)d_in[3];
  const float* a0   = (const float*)d_in[4];
  const float* W1   = (const float*)d_in[5];
  const float* a1   = (const float*)d_in[6];
  const float* rp0w = (const float*)d_in[7];
  const float* rp0b = (const float*)d_in[8];
  const float* rp1w = (const float*)d_in[9];
  const float* rp1b = (const float*)d_in[10];
  const float* ln0g = (const float*)d_in[11];
  const float* ln0b = (const float*)d_in[12];
  const float* ln1g = (const float*)d_in[13];
  const float* ln1b = (const float*)d_in[14];
  float* out = (float*)d_out;
  char* wsb = (char*)d_ws;

  // ---- workspace layout (bytes) ----
  constexpr size_t OFF_XBF   = 0;             // [4096][768]    bf16   6291456
  constexpr size_t OFF_W0T   = 6291456;       // [2048][768]    bf16   3145728
  constexpr size_t OFF_RP0WT = 9437184;       // [2048][768]    bf16   3145728
  constexpr size_t OFF_W1T   = 12582912;      // [3072][2048]   bf16  12582912
  constexpr size_t OFF_RP1WT = 25165824;      // [768][2048]    bf16   3145728
  constexpr size_t OFF_WA0   = 28311552;
  constexpr size_t OFF_WA1   = 28336128;
  constexpr size_t OFF_S0    = 28401664;
  constexpr size_t OFF_S1    = 28532736;
  constexpr size_t OFF_L0    = 28664320;
  constexpr size_t OFF_L1    = 28729856;
  constexpr size_t OFF_H1B   = 28795392;      // [4096][2048] bf16   16777216
  constexpr size_t D         = 45572608;      // dynamic region
  // layer0: WH0T [2048][4096] fp8 @D;  RP0 [4096][2048] f32 @D+16777216
  // layer1: WH1T [3072][4096] fp8 @D;  RP1 [4096][768]  f32 @D+25165824
  constexpr size_t PD        = D + 50331648;          // P @ 95904256, 4 x 16777216 fp8
  constexpr size_t PN        = (size_t)NN * NN;
  constexpr size_t OFF_HP1   = PD + 4 * PN;           // [4][4096][768] f32 -> ends 213344768
  // ACC0 [4096][2048] f32 (33.5 MB) aliases the HP1 region (layer-0 use only).

  u16*   XBF   = (u16*)(wsb + OFF_XBF);
  u16*   W0T   = (u16*)(wsb + OFF_W0T);
  u16*   RP0WT = (u16*)(wsb + OFF_RP0WT);
  u16*   W1T   = (u16*)(wsb + OFF_W1T);
  u16*   RP1WT = (u16*)(wsb + OFF_RP1WT);
  float* WA0   = (float*)(wsb + OFF_WA0);
  float* WA1   = (float*)(wsb + OFF_WA1);
  float* S0    = (float*)(wsb + OFF_S0);
  float* S1    = (float*)(wsb + OFF_S1);
  float* L0    = (float*)(wsb + OFF_L0);
  float* L1    = (float*)(wsb + OFF_L1);
  u16*   H1B   = (u16*)(wsb + OFF_H1B);
  u8*    WH0T  = (u8*)(wsb + D);
  float* RP0   = (float*)(wsb + D + 16777216);
  u8*    WH1T  = (u8*)(wsb + D);
  float* RP1   = (float*)(wsb + D + 25165824);
  u8*    P     = (u8*)(wsb + PD);
  float* HP1   = (float*)(wsb + OFF_HP1);
  float* ACC0  = (float*)(wsb + OFF_HP1);     // alias, layer-0 only

  const int G = (ws_size >= OFF_HP1 + 50331648) ? 4 : 1;

  // ---- prep ----
  cast_f32_bf16<<<dim3((NN * 768 + 255) / 256), 256, 0, stream>>>(X, XBF, NN * 768);
  transcast_f32<<<dim3(16, 24, 4), 256, 0, stream>>>(W0, W0T, 768, 512);
  transcast_f32<<<dim3(24, 64, 4), 256, 0, stream>>>(W1, W1T, 2048, 768);
  transcast_f32<<<dim3(64, 24, 1), 256, 0, stream>>>(rp0w, RP0WT, 768, 2048);
  transcast_f32<<<dim3(24, 64, 1), 256, 0, stream>>>(rp1w, RP1WT, 2048, 768);

  // ---- layer 0 attention scalars (fp32 exact) ----
  wa_kernel<<<dim3(2 * NHEADS * 768 / 4), 256, 0, stream>>>(W0, a0, WA0, 768, 512);
  s8_kernel_f32<<<dim3(NN / 4), 256, 0, stream>>>(X, WA0, S0, 768);

  // ---- layer 0: merged projections (Wh0^T fp8 + RP0 fp32+bias), one launch ----
  gemm_proj<<<dim3(32, 32), 256, 0, stream>>>(XBF, W0T, WH0T, RP0, rp0b, 768, 2048, 2048);

  // zero ACC0, then per head-group: P' then ACC0[:, h*512:] += raw P'@Wh0 (split-K=2 atomics)
  hipMemsetAsync(ACC0, 0, (size_t)NN * 2048 * 4, stream);
  for (int g = 0; g < NHEADS; g += G) {
    if (G == 4) pexp_g_kernel<4><<<dim3(NN), 256, 0, stream>>>(adj, ew, S0, P, L0, g);
    else        pexp_g_kernel<1><<<dim3(NN), 256, 0, stream>>>(adj, ew, S0, P, L0, g);
    gemm_fp8<2><<<dim3(32, 4, 2 * G), 256, 0, stream>>>(P, WH0T + (size_t)g * 512 * NN,
        ACC0, 2048, g * 512, 512, (size_t)512 * NN, 0);
  }
  ln0_kernel<<<dim3(NN), 256, 0, stream>>>(ACC0, RP0, L0, ln0g, ln0b, H1B);

  // ---- layer 1 attention scalars ----
  wa_kernel<<<dim3(2 * NHEADS * 2048 / 4), 256, 0, stream>>>(W1, a1, WA1, 2048, 768);
  s8_kernel_bf16<<<dim3(NN / 4), 256, 0, stream>>>(H1B, WA1, S1, 2048);

  // ---- layer 1: merged projections (Wh1^T fp8 + RP1 fp32+bias), one launch ----
  gemm_proj<<<dim3(32, 30), 256, 0, stream>>>(H1B, W1T, WH1T, RP1, rp1b, 2048, 3072, 768);

  // zero HP1, then per head-group: P' then HP1[h] += raw P'@Wh1 (split-K=2 atomics)
  hipMemsetAsync(HP1, 0, (size_t)NHEADS * NN * 768 * 4, stream);
  for (int g = 0; g < NHEADS; g += G) {
    if (G == 4) pexp_g_kernel<4><<<dim3(NN), 256, 0, stream>>>(adj, ew, S1, P, L1, g);
    else        pexp_g_kernel<1><<<dim3(NN), 256, 0, stream>>>(adj, ew, S1, P, L1, g);
    gemm_fp8<3><<<dim3(32, 6, 2 * G), 256, 0, stream>>>(P, WH1T + (size_t)g * 768 * NN,
        HP1 + (size_t)g * NN * 768, 768, 0, 0, (size_t)768 * NN, (size_t)NN * 768);
  }
  ln1_kernel<<<dim3(NN), 256, 0, stream>>>(HP1, RP1, L1, ln1g, ln1b, out);
}

// Round 9
// 684.956 us; speedup vs baseline: 1.1336x; 1.1336x over previous
//
#include <hip/hip_runtime.h>

// ============================================================================
// KnowledgeGraphEncoder: 2-layer dense GAT, N=4096, H=4.
// bf16 MFMA merged projection GEMMs (BK=64, XOR-swizzled LDS);
// MX-fp8 (e4m3, unit scales) mfma_scale 16x16x128 attention GEMMs, BK=128,
// XOR-swizzled LDS, raw plain-store epilogue (scale/elu folded into LN);
// fused 8-way s-kernels; XCD-aware grids. ws ~213 MB.
// ============================================================================

typedef unsigned short u16;
typedef unsigned char u8;
using short8  = __attribute__((ext_vector_type(8))) short;
using float4v = __attribute__((ext_vector_type(4))) float;
using int4v   = __attribute__((ext_vector_type(4))) int;
using int8v   = __attribute__((ext_vector_type(8))) int;

#define NN 4096
#define NHEADS 4

__device__ __forceinline__ u16 f2bf(float f) {
  union { float f; unsigned u; } v; v.f = f;
  unsigned u = v.u;
  return (u16)((u + 0x7FFFu + ((u >> 16) & 1u)) >> 16);   // RNE
}
__device__ __forceinline__ float bf2f(u16 x) {
  union { unsigned u; float f; } v; v.u = ((unsigned)x) << 16; return v.f;
}
// pack 4 floats -> 4 fp8 e4m3 bytes (HW cvt, OCP on gfx950)
__device__ __forceinline__ unsigned pk_fp8x4(float a, float b, float c, float d) {
  int lo = __builtin_amdgcn_cvt_pk_fp8_f32(a, b, 0, false);
  return (unsigned)__builtin_amdgcn_cvt_pk_fp8_f32(c, d, lo, true);
}

// async global->LDS, 16B per lane, LDS dest = wave-uniform base + lane*16
__device__ __forceinline__ void async16(const void* g, void* l) {
  __builtin_amdgcn_global_load_lds(
      (const __attribute__((address_space(1))) unsigned int*)g,
      (__attribute__((address_space(3))) unsigned int*)l, 16, 0, 0);
}

// ---------------------------------------------------------------- cast fp32->bf16
__global__ __launch_bounds__(256) void cast_f32_bf16(const float* __restrict__ in,
                                                     u16* __restrict__ out, int n) {
  int i = blockIdx.x * 256 + threadIdx.x;
  if (i < n) out[i] = f2bf(in[i]);
}

// ------------------------------------------------- transpose+cast fp32 -> bf16
// in [z][R][C] -> out [z][C][R]
__global__ __launch_bounds__(256) void transcast_f32(const float* __restrict__ in,
                                                     u16* __restrict__ out, int R, int C) {
  __shared__ float t[32][33];
  size_t zoff = (size_t)blockIdx.z * R * C;
  in += zoff; out += zoff;
  int c0 = blockIdx.x * 32, r0 = blockIdx.y * 32;
  int tx = threadIdx.x & 31, ty = threadIdx.x >> 5;
#pragma unroll
  for (int i = 0; i < 32; i += 8)
    t[ty + i][tx] = in[(size_t)(r0 + ty + i) * C + (c0 + tx)];
  __syncthreads();
#pragma unroll
  for (int i = 0; i < 32; i += 8)
    out[(size_t)(c0 + ty + i) * R + (r0 + tx)] = f2bf(t[tx][ty + i]);
}

// ------------------------------------------------- wa[side][h][f] = sum_o W[h][f][o]*a[h][side*O+o]
__global__ __launch_bounds__(256) void wa_kernel(const float* __restrict__ W,
                                                 const float* __restrict__ a,
                                                 float* __restrict__ wa, int F, int O) {
  int gw = blockIdx.x * 4 + (threadIdx.x >> 6);
  int lane = threadIdx.x & 63;
  int total = 2 * NHEADS * F;
  if (gw >= total) return;
  int side = gw / (NHEADS * F);
  int rem = gw - side * NHEADS * F;
  int h = rem / F, f = rem - h * F;
  const float* wrow = W + ((size_t)h * F + f) * O;
  const float* av = a + (size_t)h * 2 * O + (size_t)side * O;
  float s = 0.f;
  for (int o = lane; o < O; o += 64) s += wrow[o] * av[o];
#pragma unroll
  for (int off = 32; off > 0; off >>= 1) s += __shfl_down(s, off);
  if (lane == 0) wa[gw] = s;
}

// ------------------------------------------------- fused 8-way s: one wave per node
__global__ __launch_bounds__(256) void s8_kernel_f32(const float* __restrict__ X,
                                                     const float* __restrict__ wa,
                                                     float* __restrict__ sout, int F) {
  int n = blockIdx.x * 4 + (threadIdx.x >> 6);
  int lane = threadIdx.x & 63;
  const float* x = X + (size_t)n * F;
  float acc[8] = {};
  for (int f = lane; f < F; f += 64) {
    float xv = x[f];
#pragma unroll
    for (int k = 0; k < 8; k++) acc[k] += xv * wa[(size_t)k * F + f];
  }
#pragma unroll
  for (int k = 0; k < 8; k++) {
    float s = acc[k];
#pragma unroll
    for (int off = 32; off > 0; off >>= 1) s += __shfl_down(s, off);
    if (lane == 0) sout[(size_t)k * NN + n] = s;
  }
}

__global__ __launch_bounds__(256) void s8_kernel_bf16(const u16* __restrict__ X,
                                                      const float* __restrict__ wa,
                                                      float* __restrict__ sout, int F) {
  int n = blockIdx.x * 4 + (threadIdx.x >> 6);
  int lane = threadIdx.x & 63;
  const u16* x = X + (size_t)n * F;
  float acc[8] = {};
  for (int f = lane; f < F; f += 64) {
    float xv = bf2f(x[f]);
#pragma unroll
    for (int k = 0; k < 8; k++) acc[k] += xv * wa[(size_t)k * F + f];
  }
#pragma unroll
  for (int k = 0; k < 8; k++) {
    float s = acc[k];
#pragma unroll
    for (int off = 32; off > 0; off >>= 1) s += __shfl_down(s, off);
    if (lane == 0) sout[(size_t)k * NN + n] = s;
  }
}

// ------------------------------------------------- G-head P' = exp(v - rowmax) fp8, l = rowsum (fp32)
template <int G>
__global__ __launch_bounds__(256) void pexp_g_kernel(const int* __restrict__ adj,
                                                     const float* __restrict__ ew,
                                                     const float* __restrict__ s,
                                                     u8* __restrict__ P,
                                                     float* __restrict__ L, int hb) {
  __shared__ float vbuf[G][NN];
  __shared__ float mred[G][4];
  __shared__ float lred[G][4];
  __shared__ float mrow[G];
  int i = blockIdx.x, tid = threadIdx.x;
  float sr[G], mx[G], lacc[G];
#pragma unroll
  for (int z = 0; z < G; z++) {
    sr[z] = s[(size_t)(hb + z) * NN + i];
    mx[z] = -3e38f;
    lacc[z] = 0.f;
  }
  const int4* arow = (const int4*)(adj + (size_t)i * NN);
  const float4* wrow = (const float4*)(ew + (size_t)i * NN);
  // pass 1: v -> LDS, row max
  for (int jv = tid; jv < NN / 4; jv += 256) {
    int4 a = arow[jv];
    float4 w = wrow[jv];
    int j0 = jv * 4;
    float we[4]; we[0] = w.x; we[1] = w.y; we[2] = w.z; we[3] = w.w;
    bool m[4];
    m[0] = (a.x != 0) || (j0 + 0 == i);
    m[1] = (a.y != 0) || (j0 + 1 == i);
    m[2] = (a.z != 0) || (j0 + 2 == i);
    m[3] = (a.w != 0) || (j0 + 3 == i);
#pragma unroll
    for (int z = 0; z < G; z++) {
      const float4 sd4 = *(const float4*)(s + (size_t)(NHEADS + hb + z) * NN + j0);
      float sd[4]; sd[0] = sd4.x; sd[1] = sd4.y; sd[2] = sd4.z; sd[3] = sd4.w;
      float4 vv;
      float* vp = (float*)&vv;
#pragma unroll
      for (int k = 0; k < 4; k++) {
        float x = sr[z] + sd[k];
        float e = x > 0.f ? x : 0.2f * x;
        float v = (m[k] ? e : -9e15f) * we[k];
        vp[k] = v;
        mx[z] = fmaxf(mx[z], v);
      }
      *(float4*)(&vbuf[z][j0]) = vv;
    }
  }
#pragma unroll
  for (int z = 0; z < G; z++) {
    float r = mx[z];
#pragma unroll
    for (int off = 32; off > 0; off >>= 1) r = fmaxf(r, __shfl_down(r, off));
    if ((tid & 63) == 0) mred[z][tid >> 6] = r;
  }
  __syncthreads();
  if (tid < G)
    mrow[tid] = fmaxf(fmaxf(mred[tid][0], mred[tid][1]), fmaxf(mred[tid][2], mred[tid][3]));
  __syncthreads();
  float mv[G];
#pragma unroll
  for (int z = 0; z < G; z++) mv[z] = mrow[z];
  // pass 2: p = exp(v - m), fp8 pack, rowsum
  for (int jv = tid; jv < NN / 4; jv += 256) {
    int j0 = jv * 4;
#pragma unroll
    for (int z = 0; z < G; z++) {
      float4 vv = *(const float4*)(&vbuf[z][j0]);
      float p0 = __expf(vv.x - mv[z]);
      float p1 = __expf(vv.y - mv[z]);
      float p2 = __expf(vv.z - mv[z]);
      float p3 = __expf(vv.w - mv[z]);
      lacc[z] += (p0 + p1) + (p2 + p3);
      *(unsigned*)(P + ((size_t)z * NN + i) * NN + j0) = pk_fp8x4(p0, p1, p2, p3);
    }
  }
#pragma unroll
  for (int z = 0; z < G; z++) {
    float r = lacc[z];
#pragma unroll
    for (int off = 32; off > 0; off >>= 1) r += __shfl_down(r, off);
    if ((tid & 63) == 0) lred[z][tid >> 6] = r;
  }
  __syncthreads();
  if (tid < G)
    L[(size_t)(hb + tid) * NN + i] = lred[tid][0] + lred[tid][1] + lred[tid][2] + lred[tid][3];
}

// ------------------------------------------------- merged projection GEMM (bf16, BK=64, XOR swizzle)
__global__ __launch_bounds__(256) void gemm_proj(const u16* __restrict__ A,
                                                 const u16* __restrict__ Bt,
                                                 u8* __restrict__ F8T,
                                                 float* __restrict__ F32,
                                                 const float* __restrict__ bias,
                                                 int K, int split, int ldcF) {
  int row0 = blockIdx.x * 128;
  int col0 = blockIdx.y * 128;

  __shared__ u16 ldsA[128 * 64];
  __shared__ u16 ldsB[128 * 64];

  int tid = threadIdx.x;
  int wave = tid >> 6, lane = tid & 63;
  int wm = wave >> 1, wn = wave & 1;
  int lm = lane & 15, quad = lane >> 4;

  int sr = tid >> 3, sc = tid & 7;
  int scg = sc ^ (sr & 7);                       // fetch swizzled global chunk
  const u16* aPtr = A  + (size_t)(row0 + sr) * K + scg * 8;
  const u16* bPtr = Bt + (size_t)(col0 + sr) * K + scg * 8;
  u16* ldsAw = &ldsA[wave * 512];
  u16* ldsBw = &ldsB[wave * 512];
  const size_t rowStep = (size_t)32 * K;

  float4v acc[4][4] = {};

  for (int k0 = 0; k0 < K; k0 += 64) {
    __syncthreads();
#pragma unroll
    for (int b = 0; b < 4; b++) {
      async16(aPtr + k0 + b * rowStep, ldsAw + b * 2048);
      async16(bPtr + k0 + b * rowStep, ldsBw + b * 2048);
    }
    __syncthreads();
    short8 af[4][2], bf[4][2];
#pragma unroll
    for (int s = 0; s < 4; s++) {
      int ra = wm * 64 + s * 16 + lm;
      int rb = wn * 64 + s * 16 + lm;
      int swa = ra & 7, swb = rb & 7;
      af[s][0] = *(const short8*)(&ldsA[ra * 64 + ((quad ^ swa) * 8)]);
      af[s][1] = *(const short8*)(&ldsA[ra * 64 + (((4 + quad) ^ swa) * 8)]);
      bf[s][0] = *(const short8*)(&ldsB[rb * 64 + ((quad ^ swb) * 8)]);
      bf[s][1] = *(const short8*)(&ldsB[rb * 64 + (((4 + quad) ^ swb) * 8)]);
    }
#pragma unroll
    for (int i = 0; i < 4; i++)
#pragma unroll
      for (int j = 0; j < 4; j++) {
        acc[i][j] = __builtin_amdgcn_mfma_f32_16x16x32_bf16(af[i][0], bf[j][0], acc[i][j], 0, 0, 0);
        acc[i][j] = __builtin_amdgcn_mfma_f32_16x16x32_bf16(af[i][1], bf[j][1], acc[i][j], 0, 0, 0);
      }
  }

  if (col0 < split) {
#pragma unroll
    for (int i = 0; i < 4; i++) {
#pragma unroll
      for (int j = 0; j < 4; j++) {
        int grow0 = row0 + wm * 64 + i * 16 + (lane >> 4) * 4;
        int gcol = col0 + wn * 64 + j * 16 + lm;
        unsigned pk = pk_fp8x4(acc[i][j][0], acc[i][j][1], acc[i][j][2], acc[i][j][3]);
        *(unsigned*)&F8T[(size_t)gcol * NN + grow0] = pk;
      }
    }
  } else {
#pragma unroll
    for (int i = 0; i < 4; i++) {
#pragma unroll
      for (int j = 0; j < 4; j++) {
#pragma unroll
        for (int r = 0; r < 4; r++) {
          int grow = row0 + wm * 64 + i * 16 + (lane >> 4) * 4 + r;
          int gcol = col0 + wn * 64 + j * 16 + lm - split;
          F32[(size_t)grow * ldcF + gcol] = acc[i][j][r] + bias[gcol];
        }
      }
    }
  }
}

// ------------------------------------------------- 128x128 MX-fp8 GEMM, BK=128, K=NN
// mfma_scale_f32_16x16x128_f8f6f4 with unit scales (0x7F) == plain fp8 math at 2x rate.
// XOR-swizzled LDS (16B chunks, c holds global chunk c^(r&7)) -> conflict-free b128 reads.
// Raw plain-store epilogue; /l, elu, 0.25 folded into LN kernels.
// MODE 2: C[grow*ldc + coloff_base + h*coloff_step + gcol] = v   (layer-0, disjoint head cols)
// MODE 3: C[h*cStride + grow*ldc + gcol] = v                     (layer-1, per-head buffer)
// Grid: (x = 32 row panels, y = col panels, z = heads).
template <int MODE>
__global__ __launch_bounds__(256) void gemm_mx(const u8* __restrict__ A,
                                               const u8* __restrict__ Bt,
                                               float* __restrict__ Cout,
                                               int ldc, int coloff_base, int coloff_step,
                                               size_t bStride, size_t cStride) {
  constexpr int K = NN;
  int h = blockIdx.z;
  const u8* Ab = A + (size_t)h * ((size_t)NN * NN);
  const u8* Bb = Bt + (size_t)h * bStride;
  int row0 = blockIdx.x * 128;
  int col0 = blockIdx.y * 128;
  int coloff = coloff_base + h * coloff_step;

  __shared__ u8 ldsA[128 * 128];   // 16 KB
  __shared__ u8 ldsB[128 * 128];   // 16 KB

  int tid = threadIdx.x;
  int wave = tid >> 6, lane = tid & 63;
  int wm = wave >> 1, wn = wave & 1;
  int lm = lane & 15, quad = lane >> 4;

  // staging: sr = tid>>3 (0..31), sc = tid&7; LDS[r][c] holds global chunk c^(r&7)
  int sr = tid >> 3, sc = tid & 7;
  int scg = sc ^ (sr & 7);
  const u8* aPtr = Ab + (size_t)(row0 + sr) * K + scg * 16;
  const u8* bPtr = Bb + (size_t)(col0 + sr) * K + scg * 16;
  u8* ldsAw = &ldsA[wave * 1024];
  u8* ldsBw = &ldsB[wave * 1024];
  const size_t rowStep = (size_t)32 * K;

  float4v acc[4][4] = {};

  for (int k0 = 0; k0 < K; k0 += 128) {
    __syncthreads();
#pragma unroll
    for (int b = 0; b < 4; b++) {
      async16(aPtr + k0 + b * rowStep, ldsAw + b * 4096);
      async16(bPtr + k0 + b * rowStep, ldsBw + b * 4096);
    }
    __syncthreads();
    int8v a32[4], b32[4];
#pragma unroll
    for (int s = 0; s < 4; s++) {
      int ra = wm * 64 + s * 16 + lm;
      int rb = wn * 64 + s * 16 + lm;
      int swa = ra & 7, swb = rb & 7;
      int4v alo = *(const int4v*)(&ldsA[ra * 128 + (((2 * quad) ^ swa) * 16)]);
      int4v ahi = *(const int4v*)(&ldsA[ra * 128 + (((2 * quad + 1) ^ swa) * 16)]);
      int4v blo = *(const int4v*)(&ldsB[rb * 128 + (((2 * quad) ^ swb) * 16)]);
      int4v bhi = *(const int4v*)(&ldsB[rb * 128 + (((2 * quad + 1) ^ swb) * 16)]);
      a32[s][0] = alo[0]; a32[s][1] = alo[1]; a32[s][2] = alo[2]; a32[s][3] = alo[3];
      a32[s][4] = ahi[0]; a32[s][5] = ahi[1]; a32[s][6] = ahi[2]; a32[s][7] = ahi[3];
      b32[s][0] = blo[0]; b32[s][1] = blo[1]; b32[s][2] = blo[2]; b32[s][3] = blo[3];
      b32[s][4] = bhi[0]; b32[s][5] = bhi[1]; b32[s][6] = bhi[2]; b32[s][7] = bhi[3];
    }
#pragma unroll
    for (int i = 0; i < 4; i++)
#pragma unroll
      for (int j = 0; j < 4; j++)
        acc[i][j] = __builtin_amdgcn_mfma_scale_f32_16x16x128_f8f6f4(
            a32[i], b32[j], acc[i][j], 0, 0, 0, 127, 0, 127);
  }

#pragma unroll
  for (int i = 0; i < 4; i++) {
#pragma unroll
    for (int j = 0; j < 4; j++) {
#pragma unroll
      for (int r = 0; r < 4; r++) {
        int grow = row0 + wm * 64 + i * 16 + quad * 4 + r;
        int gcol = col0 + wn * 64 + j * 16 + lm;
        float v = acc[i][j][r];
        if constexpr (MODE == 2) {
          Cout[(size_t)grow * ldc + coloff + gcol] = v;
        } else {
          Cout[(size_t)h * cStride + (size_t)grow * ldc + gcol] = v;
        }
      }
    }
  }
}

// ------------------------------------------------- LN layer 0: x = RP0 + elu(ACC0/l) -> LN -> elu -> bf16
__global__ __launch_bounds__(256) void ln0_kernel(const float* __restrict__ accin,
                                                  const float* __restrict__ rp,
                                                  const float* __restrict__ Lsum,
                                                  const float* __restrict__ g,
                                                  const float* __restrict__ b,
                                                  u16* __restrict__ h1b) {
  const int C = 2048;
  int n = blockIdx.x, tid = threadIdx.x;
  __shared__ float xs[2048];
  __shared__ float red[2][4];
  __shared__ float mrs[2];
  float linv[NHEADS];
#pragma unroll
  for (int h = 0; h < NHEADS; h++) linv[h] = 1.0f / Lsum[(size_t)h * NN + n];
  float sum = 0.f, sq = 0.f;
  const float* ar = accin + (size_t)n * C;
  const float* rr = rp + (size_t)n * C;
  for (int c = tid; c < C; c += 256) {
    float v = ar[c] * linv[c >> 9];
    v = v > 0.f ? v : (__expf(v) - 1.f);
    float x = v + rr[c];
    xs[c] = x; sum += x; sq += x * x;
  }
#pragma unroll
  for (int off = 32; off > 0; off >>= 1) { sum += __shfl_down(sum, off); sq += __shfl_down(sq, off); }
  if ((tid & 63) == 0) { red[0][tid >> 6] = sum; red[1][tid >> 6] = sq; }
  __syncthreads();
  if (tid == 0) {
    float s = red[0][0] + red[0][1] + red[0][2] + red[0][3];
    float q = red[1][0] + red[1][1] + red[1][2] + red[1][3];
    float mean = s / C, var = q / C - mean * mean;
    mrs[0] = mean; mrs[1] = rsqrtf(var + 1e-5f);
  }
  __syncthreads();
  float mean = mrs[0], rstd = mrs[1];
  for (int c = tid; c < C; c += 256) {
    float y = (xs[c] - mean) * rstd * g[c] + b[c];
    float z = y > 0.f ? y : (__expf(y) - 1.f);
    h1b[(size_t)n * C + c] = f2bf(z);
  }
}

// ------------------------------------------------- LN layer 1: x = 0.25*sum_h HP1[h]/l1[h] + rp1 -> LN
__global__ __launch_bounds__(256) void ln1_kernel(const float* __restrict__ hp1,
                                                  const float* __restrict__ rp1,
                                                  const float* __restrict__ Lsum,
                                                  const float* __restrict__ g,
                                                  const float* __restrict__ b,
                                                  float* __restrict__ out) {
  const int C = 768;
  int n = blockIdx.x, tid = threadIdx.x;
  __shared__ float xs[768];
  __shared__ float red[2][4];
  __shared__ float mrs[2];
  float linv[NHEADS];
#pragma unroll
  for (int h = 0; h < NHEADS; h++) linv[h] = 0.25f / Lsum[(size_t)h * NN + n];
  float sum = 0.f, sq = 0.f;
  for (int c = tid; c < C; c += 256) {
    float x = hp1[((size_t)0 * NN + n) * C + c] * linv[0] +
              hp1[((size_t)1 * NN + n) * C + c] * linv[1] +
              hp1[((size_t)2 * NN + n) * C + c] * linv[2] +
              hp1[((size_t)3 * NN + n) * C + c] * linv[3];
    x += rp1[(size_t)n * C + c];     // bias already folded into rp1 by gemm_proj
    xs[c] = x; sum += x; sq += x * x;
  }
#pragma unroll
  for (int off = 32; off > 0; off >>= 1) { sum += __shfl_down(sum, off); sq += __shfl_down(sq, off); }
  if ((tid & 63) == 0) { red[0][tid >> 6] = sum; red[1][tid >> 6] = sq; }
  __syncthreads();
  if (tid == 0) {
    float s = red[0][0] + red[0][1] + red[0][2] + red[0][3];
    float q = red[1][0] + red[1][1] + red[1][2] + red[1][3];
    float mean = s / C, var = q / C - mean * mean;
    mrs[0] = mean; mrs[1] = rsqrtf(var + 1e-5f);
  }
  __syncthreads();
  float mean = mrs[0], rstd = mrs[1];
  for (int c = tid; c < C; c += 256)
    out[(size_t)n * C + c] = (xs[c] - mean) * rstd * g[c] + b[c];
}

// ============================================================================
extern "C" void kernel_launch(void* const* d_in, const int* in_sizes, int n_in,
                              void* d_out, int out_size, void* d_ws, size_t ws_size,
                              hipStream_t stream) {
  (void)in_sizes; (void)n_in; (void)out_size;
  const float* X    = (const float*)d_in[0];
  const int*   adj  = (const int*)d_in[1];
  const float* ew   = (const float*)d_in[2];
  const float* W0   = (const float*)d_in[3];
  const float* a0   = (const float*)d_in[4];
  const float* W1   = (const float*)d_in[5];
  const float* a1   = (const float*)d_in[6];
  const float* rp0w = (const float*)d_in[7];
  const float* rp0b = (const float*)d_in[8];
  const float* rp1w = (const float*)d_in[9];
  const float* rp1b = (const float*)d_in[10];
  const float* ln0g = (const float*)d_in[11];
  const float* ln0b = (const float*)d_in[12];
  const float* ln1g = (const float*)d_in[13];
  const float* ln1b = (const float*)d_in[14];
  float* out = (float*)d_out;
  char* wsb = (char*)d_ws;

  // ---- workspace layout (bytes) ----
  constexpr size_t OFF_XBF   = 0;             // [4096][768]    bf16   6291456
  constexpr size_t OFF_W0T   = 6291456;       // [2048][768]    bf16   3145728
  constexpr size_t OFF_RP0WT = 9437184;       // [2048][768]    bf16   3145728
  constexpr size_t OFF_W1T   = 12582912;      // [3072][2048]   bf16  12582912
  constexpr size_t OFF_RP1WT = 25165824;      // [768][2048]    bf16   3145728
  constexpr size_t OFF_WA0   = 28311552;
  constexpr size_t OFF_WA1   = 28336128;
  constexpr size_t OFF_S0    = 28401664;
  constexpr size_t OFF_S1    = 28532736;
  constexpr size_t OFF_L0    = 28664320;
  constexpr size_t OFF_L1    = 28729856;
  constexpr size_t OFF_H1B   = 28795392;      // [4096][2048] bf16   16777216
  constexpr size_t D         = 45572608;      // dynamic region
  // layer0: WH0T [2048][4096] fp8 @D;  RP0 [4096][2048] f32 @D+16777216
  // layer1: WH1T [3072][4096] fp8 @D;  RP1 [4096][768]  f32 @D+25165824
  constexpr size_t PD        = D + 50331648;          // P @ 95904256, 4 x 16777216 fp8
  constexpr size_t PN        = (size_t)NN * NN;
  constexpr size_t OFF_HP1   = PD + 4 * PN;           // [4][4096][768] f32 -> ends 213344768
  // ACC0 [4096][2048] f32 (33.5 MB) aliases the HP1 region (layer-0 use only).

  u16*   XBF   = (u16*)(wsb + OFF_XBF);
  u16*   W0T   = (u16*)(wsb + OFF_W0T);
  u16*   RP0WT = (u16*)(wsb + OFF_RP0WT);
  u16*   W1T   = (u16*)(wsb + OFF_W1T);
  u16*   RP1WT = (u16*)(wsb + OFF_RP1WT);
  float* WA0   = (float*)(wsb + OFF_WA0);
  float* WA1   = (float*)(wsb + OFF_WA1);
  float* S0    = (float*)(wsb + OFF_S0);
  float* S1    = (float*)(wsb + OFF_S1);
  float* L0    = (float*)(wsb + OFF_L0);
  float* L1    = (float*)(wsb + OFF_L1);
  u16*   H1B   = (u16*)(wsb + OFF_H1B);
  u8*    WH0T  = (u8*)(wsb + D);
  float* RP0   = (float*)(wsb + D + 16777216);
  u8*    WH1T  = (u8*)(wsb + D);
  float* RP1   = (float*)(wsb + D + 25165824);
  u8*    P     = (u8*)(wsb + PD);
  float* HP1   = (float*)(wsb + OFF_HP1);
  float* ACC0  = (float*)(wsb + OFF_HP1);     // alias, layer-0 only

  const int G = (ws_size >= OFF_HP1 + 50331648) ? 4 : 1;

  // ---- prep ----
  cast_f32_bf16<<<dim3((NN * 768 + 255) / 256), 256, 0, stream>>>(X, XBF, NN * 768);
  transcast_f32<<<dim3(16, 24, 4), 256, 0, stream>>>(W0, W0T, 768, 512);
  transcast_f32<<<dim3(24, 64, 4), 256, 0, stream>>>(W1, W1T, 2048, 768);
  transcast_f32<<<dim3(64, 24, 1), 256, 0, stream>>>(rp0w, RP0WT, 768, 2048);
  transcast_f32<<<dim3(24, 64, 1), 256, 0, stream>>>(rp1w, RP1WT, 2048, 768);

  // ---- layer 0 attention scalars (fp32 exact) ----
  wa_kernel<<<dim3(2 * NHEADS * 768 / 4), 256, 0, stream>>>(W0, a0, WA0, 768, 512);
  s8_kernel_f32<<<dim3(NN / 4), 256, 0, stream>>>(X, WA0, S0, 768);

  // ---- layer 0: merged projections (Wh0^T fp8 + RP0 fp32+bias), one launch ----
  gemm_proj<<<dim3(32, 32), 256, 0, stream>>>(XBF, W0T, WH0T, RP0, rp0b, 768, 2048, 2048);

  // per head-group: P' then ACC0[:, h*512:] = raw P'@Wh0 (MX-fp8, plain store)
  for (int g = 0; g < NHEADS; g += G) {
    if (G == 4) pexp_g_kernel<4><<<dim3(NN), 256, 0, stream>>>(adj, ew, S0, P, L0, g);
    else        pexp_g_kernel<1><<<dim3(NN), 256, 0, stream>>>(adj, ew, S0, P, L0, g);
    gemm_mx<2><<<dim3(32, 4, G), 256, 0, stream>>>(P, WH0T + (size_t)g * 512 * NN,
        ACC0, 2048, g * 512, 512, (size_t)512 * NN, 0);
  }
  ln0_kernel<<<dim3(NN), 256, 0, stream>>>(ACC0, RP0, L0, ln0g, ln0b, H1B);

  // ---- layer 1 attention scalars ----
  wa_kernel<<<dim3(2 * NHEADS * 2048 / 4), 256, 0, stream>>>(W1, a1, WA1, 2048, 768);
  s8_kernel_bf16<<<dim3(NN / 4), 256, 0, stream>>>(H1B, WA1, S1, 2048);

  // ---- layer 1: merged projections (Wh1^T fp8 + RP1 fp32+bias), one launch ----
  gemm_proj<<<dim3(32, 30), 256, 0, stream>>>(H1B, W1T, WH1T, RP1, rp1b, 2048, 3072, 768);

  // per head-group: P' then HP1[h] = raw P'@Wh1 (MX-fp8, plain store)
  for (int g = 0; g < NHEADS; g += G) {
    if (G == 4) pexp_g_kernel<4><<<dim3(NN), 256, 0, stream>>>(adj, ew, S1, P, L1, g);
    else        pexp_g_kernel<1><<<dim3(NN), 256, 0, stream>>>(adj, ew, S1, P, L1, g);
    gemm_mx<3><<<dim3(32, 6, G), 256, 0, stream>>>(P, WH1T + (size_t)g * 768 * NN,
        HP1 + (size_t)g * NN * 768, 768, 0, 0, (size_t)768 * NN, (size_t)NN * 768);
  }
  ln1_kernel<<<dim3(NN), 256, 0, stream>>>(HP1, RP1, L1, ln1g, ln1b, out);
}

// Round 10
// 642.167 us; speedup vs baseline: 1.2091x; 1.0666x over previous
//
#include <hip/hip_runtime.h>

// ============================================================================
// KnowledgeGraphEncoder: 2-layer dense GAT, N=4096, H=4.
// bf16 MFMA merged projection GEMMs (BK=64, XOR-swizzled LDS);
// MX-fp8 (e4m3, unit scales) mfma_scale 16x16x128 attention GEMMs, BK=128;
// single-pass pexp with analytic row-max bound + 1-bit adjacency bitmask;
// fused 8-way s-kernels; XCD-aware grids. ws ~215 MB (>=230 MB proven, R3 G=4).
// ============================================================================

typedef unsigned short u16;
typedef unsigned char u8;
typedef unsigned long long u64;
using short8  = __attribute__((ext_vector_type(8))) short;
using float4v = __attribute__((ext_vector_type(4))) float;
using int4v   = __attribute__((ext_vector_type(4))) int;
using int8v   = __attribute__((ext_vector_type(8))) int;

#define NN 4096
#define NHEADS 4

__device__ __forceinline__ u16 f2bf(float f) {
  union { float f; unsigned u; } v; v.f = f;
  unsigned u = v.u;
  return (u16)((u + 0x7FFFu + ((u >> 16) & 1u)) >> 16);   // RNE
}
__device__ __forceinline__ float bf2f(u16 x) {
  union { unsigned u; float f; } v; v.u = ((unsigned)x) << 16; return v.f;
}
// pack 4 floats -> 4 fp8 e4m3 bytes (HW cvt, OCP on gfx950)
__device__ __forceinline__ unsigned pk_fp8x4(float a, float b, float c, float d) {
  int lo = __builtin_amdgcn_cvt_pk_fp8_f32(a, b, 0, false);
  return (unsigned)__builtin_amdgcn_cvt_pk_fp8_f32(c, d, lo, true);
}

// async global->LDS, 16B per lane, LDS dest = wave-uniform base + lane*16
__device__ __forceinline__ void async16(const void* g, void* l) {
  __builtin_amdgcn_global_load_lds(
      (const __attribute__((address_space(1))) unsigned int*)g,
      (__attribute__((address_space(3))) unsigned int*)l, 16, 0, 0);
}

// ---------------------------------------------------------------- cast fp32->bf16
__global__ __launch_bounds__(256) void cast_f32_bf16(const float* __restrict__ in,
                                                     u16* __restrict__ out, int n) {
  int i = blockIdx.x * 256 + threadIdx.x;
  if (i < n) out[i] = f2bf(in[i]);
}

// ------------------------------------------------- adj int32 -> bitmask (1 bit/entry)
// bits[w] bit k = (adj[w*64 + k] != 0); one u64 word per wave via ballot.
__global__ __launch_bounds__(256) void adj2bits(const int* __restrict__ adj,
                                                u64* __restrict__ bits) {
  size_t gw = (size_t)blockIdx.x * 4 + (threadIdx.x >> 6);
  int lane = threadIdx.x & 63;
  int v = adj[gw * 64 + lane];
  u64 b = __ballot(v != 0);
  if (lane == 0) bits[gw] = b;
}

// ------------------------------------------------- transpose+cast fp32 -> bf16
// in [z][R][C] -> out [z][C][R]
__global__ __launch_bounds__(256) void transcast_f32(const float* __restrict__ in,
                                                     u16* __restrict__ out, int R, int C) {
  __shared__ float t[32][33];
  size_t zoff = (size_t)blockIdx.z * R * C;
  in += zoff; out += zoff;
  int c0 = blockIdx.x * 32, r0 = blockIdx.y * 32;
  int tx = threadIdx.x & 31, ty = threadIdx.x >> 5;
#pragma unroll
  for (int i = 0; i < 32; i += 8)
    t[ty + i][tx] = in[(size_t)(r0 + ty + i) * C + (c0 + tx)];
  __syncthreads();
#pragma unroll
  for (int i = 0; i < 32; i += 8)
    out[(size_t)(c0 + ty + i) * R + (r0 + tx)] = f2bf(t[tx][ty + i]);
}

// ------------------------------------------------- wa[side][h][f] = sum_o W[h][f][o]*a[h][side*O+o]
__global__ __launch_bounds__(256) void wa_kernel(const float* __restrict__ W,
                                                 const float* __restrict__ a,
                                                 float* __restrict__ wa, int F, int O) {
  int gw = blockIdx.x * 4 + (threadIdx.x >> 6);
  int lane = threadIdx.x & 63;
  int total = 2 * NHEADS * F;
  if (gw >= total) return;
  int side = gw / (NHEADS * F);
  int rem = gw - side * NHEADS * F;
  int h = rem / F, f = rem - h * F;
  const float* wrow = W + ((size_t)h * F + f) * O;
  const float* av = a + (size_t)h * 2 * O + (size_t)side * O;
  float s = 0.f;
  for (int o = lane; o < O; o += 64) s += wrow[o] * av[o];
#pragma unroll
  for (int off = 32; off > 0; off >>= 1) s += __shfl_down(s, off);
  if (lane == 0) wa[gw] = s;
}

// ------------------------------------------------- fused 8-way s: one wave per node
__global__ __launch_bounds__(256) void s8_kernel_f32(const float* __restrict__ X,
                                                     const float* __restrict__ wa,
                                                     float* __restrict__ sout, int F) {
  int n = blockIdx.x * 4 + (threadIdx.x >> 6);
  int lane = threadIdx.x & 63;
  const float* x = X + (size_t)n * F;
  float acc[8] = {};
  for (int f = lane; f < F; f += 64) {
    float xv = x[f];
#pragma unroll
    for (int k = 0; k < 8; k++) acc[k] += xv * wa[(size_t)k * F + f];
  }
#pragma unroll
  for (int k = 0; k < 8; k++) {
    float s = acc[k];
#pragma unroll
    for (int off = 32; off > 0; off >>= 1) s += __shfl_down(s, off);
    if (lane == 0) sout[(size_t)k * NN + n] = s;
  }
}

__global__ __launch_bounds__(256) void s8_kernel_bf16(const u16* __restrict__ X,
                                                      const float* __restrict__ wa,
                                                      float* __restrict__ sout, int F) {
  int n = blockIdx.x * 4 + (threadIdx.x >> 6);
  int lane = threadIdx.x & 63;
  const u16* x = X + (size_t)n * F;
  float acc[8] = {};
  for (int f = lane; f < F; f += 64) {
    float xv = bf2f(x[f]);
#pragma unroll
    for (int k = 0; k < 8; k++) acc[k] += xv * wa[(size_t)k * F + f];
  }
#pragma unroll
  for (int k = 0; k < 8; k++) {
    float s = acc[k];
#pragma unroll
    for (int off = 32; off > 0; off >>= 1) s += __shfl_down(s, off);
    if (lane == 0) sout[(size_t)k * NN + n] = s;
  }
}

// ------------------------------------------------- sdmax[h] = max_n sdst[h][n]
__global__ __launch_bounds__(256) void sdmax_kernel(const float* __restrict__ s,
                                                    float* __restrict__ out) {
  int h = blockIdx.x, tid = threadIdx.x;
  const float* sd = s + (size_t)(NHEADS + h) * NN;
  float m = -3e38f;
  for (int i = tid; i < NN; i += 256) m = fmaxf(m, sd[i]);
  __shared__ float red[4];
#pragma unroll
  for (int off = 32; off > 0; off >>= 1) m = fmaxf(m, __shfl_down(m, off));
  if ((tid & 63) == 0) red[tid >> 6] = m;
  __syncthreads();
  if (tid == 0) out[h] = fmaxf(fmaxf(red[0], red[1]), fmaxf(red[2], red[3]));
}

// ------------------------------------------------- single-pass G-head P' = exp(v - m') fp8
// m'[h][i] = max(0, sr[h][i] + sdmax[h]) >= true row max (proof: v_j = e_j*w_j with
// w in [0,1]; e_j <= lrelu(sr+sdmax); softmax shift-invariant; fp8 is relative-error).
// Row adjacency from 2MB bitmask, cached 512B/row in LDS.
template <int G>
__global__ __launch_bounds__(256) void pexp_g_kernel(const u64* __restrict__ mb,
                                                     const float* __restrict__ ew,
                                                     const float* __restrict__ s,
                                                     const float* __restrict__ sdmax,
                                                     u8* __restrict__ P,
                                                     float* __restrict__ L, int hb) {
  __shared__ u64 mrow[64];
  __shared__ float lred[G][4];
  int i = blockIdx.x, tid = threadIdx.x;
  if (tid < 64) mrow[tid] = mb[(size_t)i * 64 + tid];
  float sr[G], mp[G], lacc[G];
#pragma unroll
  for (int z = 0; z < G; z++) {
    sr[z] = s[(size_t)(hb + z) * NN + i];
    mp[z] = fmaxf(0.0f, sr[z] + sdmax[hb + z]);
    lacc[z] = 0.f;
  }
  const float4* wrow = (const float4*)(ew + (size_t)i * NN);
  __syncthreads();
  for (int jv = tid; jv < NN / 4; jv += 256) {
    float4 w = wrow[jv];
    int j0 = jv * 4;
    u64 mw = mrow[jv >> 4] >> (j0 & 63);
    float we[4]; we[0] = w.x; we[1] = w.y; we[2] = w.z; we[3] = w.w;
    bool m[4];
#pragma unroll
    for (int k = 0; k < 4; k++) m[k] = ((mw >> k) & 1ull) || (j0 + k == i);
#pragma unroll
    for (int z = 0; z < G; z++) {
      const float4 sd4 = *(const float4*)(s + (size_t)(NHEADS + hb + z) * NN + j0);
      float sd[4]; sd[0] = sd4.x; sd[1] = sd4.y; sd[2] = sd4.z; sd[3] = sd4.w;
      float p[4];
#pragma unroll
      for (int k = 0; k < 4; k++) {
        float x = sr[z] + sd[k];
        float e = x > 0.f ? x : 0.2f * x;
        float v = (m[k] ? e : -9e15f) * we[k];
        p[k] = __expf(v - mp[z]);
        lacc[z] += p[k];
      }
      *(unsigned*)(P + ((size_t)z * NN + i) * NN + j0) = pk_fp8x4(p[0], p[1], p[2], p[3]);
    }
  }
#pragma unroll
  for (int z = 0; z < G; z++) {
    float r = lacc[z];
#pragma unroll
    for (int off = 32; off > 0; off >>= 1) r += __shfl_down(r, off);
    if ((tid & 63) == 0) lred[z][tid >> 6] = r;
  }
  __syncthreads();
  if (tid < G)
    L[(size_t)(hb + tid) * NN + i] = lred[tid][0] + lred[tid][1] + lred[tid][2] + lred[tid][3];
}

// ------------------------------------------------- merged projection GEMM (bf16, BK=64, XOR swizzle)
__global__ __launch_bounds__(256) void gemm_proj(const u16* __restrict__ A,
                                                 const u16* __restrict__ Bt,
                                                 u8* __restrict__ F8T,
                                                 float* __restrict__ F32,
                                                 const float* __restrict__ bias,
                                                 int K, int split, int ldcF) {
  int row0 = blockIdx.x * 128;
  int col0 = blockIdx.y * 128;

  __shared__ u16 ldsA[128 * 64];
  __shared__ u16 ldsB[128 * 64];

  int tid = threadIdx.x;
  int wave = tid >> 6, lane = tid & 63;
  int wm = wave >> 1, wn = wave & 1;
  int lm = lane & 15, quad = lane >> 4;

  int sr = tid >> 3, sc = tid & 7;
  int scg = sc ^ (sr & 7);                       // fetch swizzled global chunk
  const u16* aPtr = A  + (size_t)(row0 + sr) * K + scg * 8;
  const u16* bPtr = Bt + (size_t)(col0 + sr) * K + scg * 8;
  u16* ldsAw = &ldsA[wave * 512];
  u16* ldsBw = &ldsB[wave * 512];
  const size_t rowStep = (size_t)32 * K;

  float4v acc[4][4] = {};

  for (int k0 = 0; k0 < K; k0 += 64) {
    __syncthreads();
#pragma unroll
    for (int b = 0; b < 4; b++) {
      async16(aPtr + k0 + b * rowStep, ldsAw + b * 2048);
      async16(bPtr + k0 + b * rowStep, ldsBw + b * 2048);
    }
    __syncthreads();
    short8 af[4][2], bf[4][2];
#pragma unroll
    for (int s = 0; s < 4; s++) {
      int ra = wm * 64 + s * 16 + lm;
      int rb = wn * 64 + s * 16 + lm;
      int swa = ra & 7, swb = rb & 7;
      af[s][0] = *(const short8*)(&ldsA[ra * 64 + ((quad ^ swa) * 8)]);
      af[s][1] = *(const short8*)(&ldsA[ra * 64 + (((4 + quad) ^ swa) * 8)]);
      bf[s][0] = *(const short8*)(&ldsB[rb * 64 + ((quad ^ swb) * 8)]);
      bf[s][1] = *(const short8*)(&ldsB[rb * 64 + (((4 + quad) ^ swb) * 8)]);
    }
#pragma unroll
    for (int i = 0; i < 4; i++)
#pragma unroll
      for (int j = 0; j < 4; j++) {
        acc[i][j] = __builtin_amdgcn_mfma_f32_16x16x32_bf16(af[i][0], bf[j][0], acc[i][j], 0, 0, 0);
        acc[i][j] = __builtin_amdgcn_mfma_f32_16x16x32_bf16(af[i][1], bf[j][1], acc[i][j], 0, 0, 0);
      }
  }

  if (col0 < split) {
#pragma unroll
    for (int i = 0; i < 4; i++) {
#pragma unroll
      for (int j = 0; j < 4; j++) {
        int grow0 = row0 + wm * 64 + i * 16 + (lane >> 4) * 4;
        int gcol = col0 + wn * 64 + j * 16 + lm;
        unsigned pk = pk_fp8x4(acc[i][j][0], acc[i][j][1], acc[i][j][2], acc[i][j][3]);
        *(unsigned*)&F8T[(size_t)gcol * NN + grow0] = pk;
      }
    }
  } else {
#pragma unroll
    for (int i = 0; i < 4; i++) {
#pragma unroll
      for (int j = 0; j < 4; j++) {
#pragma unroll
        for (int r = 0; r < 4; r++) {
          int grow = row0 + wm * 64 + i * 16 + (lane >> 4) * 4 + r;
          int gcol = col0 + wn * 64 + j * 16 + lm - split;
          F32[(size_t)grow * ldcF + gcol] = acc[i][j][r] + bias[gcol];
        }
      }
    }
  }
}

// ------------------------------------------------- 128x128 MX-fp8 GEMM, BK=128, K=NN
// mfma_scale_f32_16x16x128_f8f6f4 with unit scales (0x7F) == plain fp8 math at 2x rate.
// XOR-swizzled LDS -> conflict-free b128 reads. Raw plain-store epilogue.
// MODE 2: C[grow*ldc + coloff_base + h*coloff_step + gcol] = v   (layer-0, disjoint head cols)
// MODE 3: C[h*cStride + grow*ldc + gcol] = v                     (layer-1, per-head buffer)
template <int MODE>
__global__ __launch_bounds__(256) void gemm_mx(const u8* __restrict__ A,
                                               const u8* __restrict__ Bt,
                                               float* __restrict__ Cout,
                                               int ldc, int coloff_base, int coloff_step,
                                               size_t bStride, size_t cStride) {
  constexpr int K = NN;
  int h = blockIdx.z;
  const u8* Ab = A + (size_t)h * ((size_t)NN * NN);
  const u8* Bb = Bt + (size_t)h * bStride;
  int row0 = blockIdx.x * 128;
  int col0 = blockIdx.y * 128;
  int coloff = coloff_base + h * coloff_step;

  __shared__ u8 ldsA[128 * 128];   // 16 KB
  __shared__ u8 ldsB[128 * 128];   // 16 KB

  int tid = threadIdx.x;
  int wave = tid >> 6, lane = tid & 63;
  int wm = wave >> 1, wn = wave & 1;
  int lm = lane & 15, quad = lane >> 4;

  int sr = tid >> 3, sc = tid & 7;
  int scg = sc ^ (sr & 7);
  const u8* aPtr = Ab + (size_t)(row0 + sr) * K + scg * 16;
  const u8* bPtr = Bb + (size_t)(col0 + sr) * K + scg * 16;
  u8* ldsAw = &ldsA[wave * 1024];
  u8* ldsBw = &ldsB[wave * 1024];
  const size_t rowStep = (size_t)32 * K;

  float4v acc[4][4] = {};

  for (int k0 = 0; k0 < K; k0 += 128) {
    __syncthreads();
#pragma unroll
    for (int b = 0; b < 4; b++) {
      async16(aPtr + k0 + b * rowStep, ldsAw + b * 4096);
      async16(bPtr + k0 + b * rowStep, ldsBw + b * 4096);
    }
    __syncthreads();
    int8v a32[4], b32[4];
#pragma unroll
    for (int s = 0; s < 4; s++) {
      int ra = wm * 64 + s * 16 + lm;
      int rb = wn * 64 + s * 16 + lm;
      int swa = ra & 7, swb = rb & 7;
      int4v alo = *(const int4v*)(&ldsA[ra * 128 + (((2 * quad) ^ swa) * 16)]);
      int4v ahi = *(const int4v*)(&ldsA[ra * 128 + (((2 * quad + 1) ^ swa) * 16)]);
      int4v blo = *(const int4v*)(&ldsB[rb * 128 + (((2 * quad) ^ swb) * 16)]);
      int4v bhi = *(const int4v*)(&ldsB[rb * 128 + (((2 * quad + 1) ^ swb) * 16)]);
      a32[s][0] = alo[0]; a32[s][1] = alo[1]; a32[s][2] = alo[2]; a32[s][3] = alo[3];
      a32[s][4] = ahi[0]; a32[s][5] = ahi[1]; a32[s][6] = ahi[2]; a32[s][7] = ahi[3];
      b32[s][0] = blo[0]; b32[s][1] = blo[1]; b32[s][2] = blo[2]; b32[s][3] = blo[3];
      b32[s][4] = bhi[0]; b32[s][5] = bhi[1]; b32[s][6] = bhi[2]; b32[s][7] = bhi[3];
    }
#pragma unroll
    for (int i = 0; i < 4; i++)
#pragma unroll
      for (int j = 0; j < 4; j++)
        acc[i][j] = __builtin_amdgcn_mfma_scale_f32_16x16x128_f8f6f4(
            a32[i], b32[j], acc[i][j], 0, 0, 0, 127, 0, 127);
  }

#pragma unroll
  for (int i = 0; i < 4; i++) {
#pragma unroll
    for (int j = 0; j < 4; j++) {
#pragma unroll
      for (int r = 0; r < 4; r++) {
        int grow = row0 + wm * 64 + i * 16 + quad * 4 + r;
        int gcol = col0 + wn * 64 + j * 16 + lm;
        float v = acc[i][j][r];
        if constexpr (MODE == 2) {
          Cout[(size_t)grow * ldc + coloff + gcol] = v;
        } else {
          Cout[(size_t)h * cStride + (size_t)grow * ldc + gcol] = v;
        }
      }
    }
  }
}

// ------------------------------------------------- LN layer 0: x = RP0 + elu(ACC0/l) -> LN -> elu -> bf16
__global__ __launch_bounds__(256) void ln0_kernel(const float* __restrict__ accin,
                                                  const float* __restrict__ rp,
                                                  const float* __restrict__ Lsum,
                                                  const float* __restrict__ g,
                                                  const float* __restrict__ b,
                                                  u16* __restrict__ h1b) {
  const int C = 2048;
  int n = blockIdx.x, tid = threadIdx.x;
  __shared__ float xs[2048];
  __shared__ float red[2][4];
  __shared__ float mrs[2];
  float linv[NHEADS];
#pragma unroll
  for (int h = 0; h < NHEADS; h++) linv[h] = 1.0f / Lsum[(size_t)h * NN + n];
  float sum = 0.f, sq = 0.f;
  const float* ar = accin + (size_t)n * C;
  const float* rr = rp + (size_t)n * C;
  for (int c = tid; c < C; c += 256) {
    float v = ar[c] * linv[c >> 9];
    v = v > 0.f ? v : (__expf(v) - 1.f);
    float x = v + rr[c];
    xs[c] = x; sum += x; sq += x * x;
  }
#pragma unroll
  for (int off = 32; off > 0; off >>= 1) { sum += __shfl_down(sum, off); sq += __shfl_down(sq, off); }
  if ((tid & 63) == 0) { red[0][tid >> 6] = sum; red[1][tid >> 6] = sq; }
  __syncthreads();
  if (tid == 0) {
    float s = red[0][0] + red[0][1] + red[0][2] + red[0][3];
    float q = red[1][0] + red[1][1] + red[1][2] + red[1][3];
    float mean = s / C, var = q / C - mean * mean;
    mrs[0] = mean; mrs[1] = rsqrtf(var + 1e-5f);
  }
  __syncthreads();
  float mean = mrs[0], rstd = mrs[1];
  for (int c = tid; c < C; c += 256) {
    float y = (xs[c] - mean) * rstd * g[c] + b[c];
    float z = y > 0.f ? y : (__expf(y) - 1.f);
    h1b[(size_t)n * C + c] = f2bf(z);
  }
}

// ------------------------------------------------- LN layer 1: x = 0.25*sum_h HP1[h]/l1[h] + rp1 -> LN
__global__ __launch_bounds__(256) void ln1_kernel(const float* __restrict__ hp1,
                                                  const float* __restrict__ rp1,
                                                  const float* __restrict__ Lsum,
                                                  const float* __restrict__ g,
                                                  const float* __restrict__ b,
                                                  float* __restrict__ out) {
  const int C = 768;
  int n = blockIdx.x, tid = threadIdx.x;
  __shared__ float xs[768];
  __shared__ float red[2][4];
  __shared__ float mrs[2];
  float linv[NHEADS];
#pragma unroll
  for (int h = 0; h < NHEADS; h++) linv[h] = 0.25f / Lsum[(size_t)h * NN + n];
  float sum = 0.f, sq = 0.f;
  for (int c = tid; c < C; c += 256) {
    float x = hp1[((size_t)0 * NN + n) * C + c] * linv[0] +
              hp1[((size_t)1 * NN + n) * C + c] * linv[1] +
              hp1[((size_t)2 * NN + n) * C + c] * linv[2] +
              hp1[((size_t)3 * NN + n) * C + c] * linv[3];
    x += rp1[(size_t)n * C + c];     // bias already folded into rp1 by gemm_proj
    xs[c] = x; sum += x; sq += x * x;
  }
#pragma unroll
  for (int off = 32; off > 0; off >>= 1) { sum += __shfl_down(sum, off); sq += __shfl_down(sq, off); }
  if ((tid & 63) == 0) { red[0][tid >> 6] = sum; red[1][tid >> 6] = sq; }
  __syncthreads();
  if (tid == 0) {
    float s = red[0][0] + red[0][1] + red[0][2] + red[0][3];
    float q = red[1][0] + red[1][1] + red[1][2] + red[1][3];
    float mean = s / C, var = q / C - mean * mean;
    mrs[0] = mean; mrs[1] = rsqrtf(var + 1e-5f);
  }
  __syncthreads();
  float mean = mrs[0], rstd = mrs[1];
  for (int c = tid; c < C; c += 256)
    out[(size_t)n * C + c] = (xs[c] - mean) * rstd * g[c] + b[c];
}

// ============================================================================
extern "C" void kernel_launch(void* const* d_in, const int* in_sizes, int n_in,
                              void* d_out, int out_size, void* d_ws, size_t ws_size,
                              hipStream_t stream) {
  (void)in_sizes; (void)n_in; (void)out_size;
  const float* X    = (const float*)d_in[0];
  const int*   adj  = (const int*)d_in[1];
  const float* ew   = (const float*)d_in[2];
  const float* W0   = (const float*)d_in[3];
  const float* a0   = (const float*)d_in[4];
  const float* W1   = (const float*)d_in[5];
  const float* a1   = (const float*)d_in[6];
  const float* rp0w = (const float*)d_in[7];
  const float* rp0b = (const float*)d_in[8];
  const float* rp1w = (const float*)d_in[9];
  const float* rp1b = (const float*)d_in[10];
  const float* ln0g = (const float*)d_in[11];
  const float* ln0b = (const float*)d_in[12];
  const float* ln1g = (const float*)d_in[13];
  const float* ln1b = (const float*)d_in[14];
  float* out = (float*)d_out;
  char* wsb = (char*)d_ws;

  // ---- workspace layout (bytes) ----
  constexpr size_t OFF_XBF   = 0;             // [4096][768]    bf16   6291456
  constexpr size_t OFF_W0T   = 6291456;       // [2048][768]    bf16   3145728
  constexpr size_t OFF_RP0WT = 9437184;       // [2048][768]    bf16   3145728
  constexpr size_t OFF_W1T   = 12582912;      // [3072][2048]   bf16  12582912
  constexpr size_t OFF_RP1WT = 25165824;      // [768][2048]    bf16   3145728
  constexpr size_t OFF_WA0   = 28311552;
  constexpr size_t OFF_WA1   = 28336128;
  constexpr size_t OFF_S0    = 28401664;
  constexpr size_t OFF_S1    = 28532736;
  constexpr size_t OFF_L0    = 28664320;
  constexpr size_t OFF_L1    = 28729856;
  constexpr size_t OFF_H1B   = 28795392;      // [4096][2048] bf16   16777216
  constexpr size_t D         = 45572608;      // dynamic region
  // layer0: WH0T [2048][4096] fp8 @D;  RP0 [4096][2048] f32 @D+16777216
  // layer1: WH1T [3072][4096] fp8 @D;  RP1 [4096][768]  f32 @D+25165824
  constexpr size_t PD        = D + 50331648;          // P @ 95904256, 4 x 16777216 fp8
  constexpr size_t PN        = (size_t)NN * NN;
  constexpr size_t OFF_HP1   = PD + 4 * PN;           // [4][4096][768] f32 -> ends 213344768
  constexpr size_t OFF_MASK  = 213344768;             // [4096][64] u64 = 2097152 -> 215441920
  constexpr size_t OFF_SM0   = 215441920;             // [4] f32 (pad 256)
  constexpr size_t OFF_SM1   = 215442176;             // [4] f32; end 215442432 < 230121984 (proven, R3 G=4)
  // ACC0 [4096][2048] f32 (33.5 MB) aliases the HP1 region (layer-0 use only).

  u16*   XBF   = (u16*)(wsb + OFF_XBF);
  u16*   W0T   = (u16*)(wsb + OFF_W0T);
  u16*   RP0WT = (u16*)(wsb + OFF_RP0WT);
  u16*   W1T   = (u16*)(wsb + OFF_W1T);
  u16*   RP1WT = (u16*)(wsb + OFF_RP1WT);
  float* WA0   = (float*)(wsb + OFF_WA0);
  float* WA1   = (float*)(wsb + OFF_WA1);
  float* S0    = (float*)(wsb + OFF_S0);
  float* S1    = (float*)(wsb + OFF_S1);
  float* L0    = (float*)(wsb + OFF_L0);
  float* L1    = (float*)(wsb + OFF_L1);
  u16*   H1B   = (u16*)(wsb + OFF_H1B);
  u8*    WH0T  = (u8*)(wsb + D);
  float* RP0   = (float*)(wsb + D + 16777216);
  u8*    WH1T  = (u8*)(wsb + D);
  float* RP1   = (float*)(wsb + D + 25165824);
  u8*    P     = (u8*)(wsb + PD);
  float* HP1   = (float*)(wsb + OFF_HP1);
  float* ACC0  = (float*)(wsb + OFF_HP1);     // alias, layer-0 only
  u64*   MASK  = (u64*)(wsb + OFF_MASK);
  float* SM0   = (float*)(wsb + OFF_SM0);
  float* SM1   = (float*)(wsb + OFF_SM1);

  const int G = (ws_size >= OFF_HP1 + 50331648) ? 4 : 1;

  // ---- prep ----
  adj2bits<<<dim3(65536), 256, 0, stream>>>(adj, MASK);
  cast_f32_bf16<<<dim3((NN * 768 + 255) / 256), 256, 0, stream>>>(X, XBF, NN * 768);
  transcast_f32<<<dim3(16, 24, 4), 256, 0, stream>>>(W0, W0T, 768, 512);
  transcast_f32<<<dim3(24, 64, 4), 256, 0, stream>>>(W1, W1T, 2048, 768);
  transcast_f32<<<dim3(64, 24, 1), 256, 0, stream>>>(rp0w, RP0WT, 768, 2048);
  transcast_f32<<<dim3(24, 64, 1), 256, 0, stream>>>(rp1w, RP1WT, 2048, 768);

  // ---- layer 0 attention scalars (fp32 exact) ----
  wa_kernel<<<dim3(2 * NHEADS * 768 / 4), 256, 0, stream>>>(W0, a0, WA0, 768, 512);
  s8_kernel_f32<<<dim3(NN / 4), 256, 0, stream>>>(X, WA0, S0, 768);
  sdmax_kernel<<<dim3(NHEADS), 256, 0, stream>>>(S0, SM0);

  // ---- layer 0: merged projections (Wh0^T fp8 + RP0 fp32+bias), one launch ----
  gemm_proj<<<dim3(32, 32), 256, 0, stream>>>(XBF, W0T, WH0T, RP0, rp0b, 768, 2048, 2048);

  // per head-group: P' then ACC0[:, h*512:] = raw P'@Wh0 (MX-fp8, plain store)
  for (int g = 0; g < NHEADS; g += G) {
    if (G == 4) pexp_g_kernel<4><<<dim3(NN), 256, 0, stream>>>(MASK, ew, S0, SM0, P, L0, g);
    else        pexp_g_kernel<1><<<dim3(NN), 256, 0, stream>>>(MASK, ew, S0, SM0, P, L0, g);
    gemm_mx<2><<<dim3(32, 4, G), 256, 0, stream>>>(P, WH0T + (size_t)g * 512 * NN,
        ACC0, 2048, g * 512, 512, (size_t)512 * NN, 0);
  }
  ln0_kernel<<<dim3(NN), 256, 0, stream>>>(ACC0, RP0, L0, ln0g, ln0b, H1B);

  // ---- layer 1 attention scalars ----
  wa_kernel<<<dim3(2 * NHEADS * 2048 / 4), 256, 0, stream>>>(W1, a1, WA1, 2048, 768);
  s8_kernel_bf16<<<dim3(NN / 4), 256, 0, stream>>>(H1B, WA1, S1, 2048);
  sdmax_kernel<<<dim3(NHEADS), 256, 0, stream>>>(S1, SM1);

  // ---- layer 1: merged projections (Wh1^T fp8 + RP1 fp32+bias), one launch ----
  gemm_proj<<<dim3(32, 30), 256, 0, stream>>>(H1B, W1T, WH1T, RP1, rp1b, 2048, 3072, 768);

  // per head-group: P' then HP1[h] = raw P'@Wh1 (MX-fp8, plain store)
  for (int g = 0; g < NHEADS; g += G) {
    if (G == 4) pexp_g_kernel<4><<<dim3(NN), 256, 0, stream>>>(MASK, ew, S1, SM1, P, L1, g);
    else        pexp_g_kernel<1><<<dim3(NN), 256, 0, stream>>>(MASK, ew, S1, SM1, P, L1, g);
    gemm_mx<3><<<dim3(32, 6, G), 256, 0, stream>>>(P, WH1T + (size_t)g * 768 * NN,
        HP1 + (size_t)g * NN * 768, 768, 0, 0, (size_t)768 * NN, (size_t)NN * 768);
  }
  ln1_kernel<<<dim3(NN), 256, 0, stream>>>(HP1, RP1, L1, ln1g, ln1b, out);
}